// Round 8
// baseline (261.574 us; speedup 1.0000x reference)
//
#include <hip/hip_runtime.h>

// CausalNet CC-loss, closed-form, scaled-linear-space scan (classic scaled-HMM).
// B=32, T=256, b=16 hardcoded.
//
//   f_t[b,tau,1] = U[b,tau] + V[b,t]  (tau < t)
//   U(b,tau) = G(tau) + st_b(tau) - AP2 - PA(tau) - Q(tau),  G(0)=0
//   V(b,t)   = PA(t) + Q(t-1) + sp0_b(t)
//   G(t)     = lse_b( R_b(t-1) + V(b,t) ),  total_logp = G(L)
//   backward e=1 channel = scalar W[t]
//   total_cc = sum_{t<=L, tau<t, b} 2^(U+V+W[t]-G(L)) * pens[beta,tau,t,b]
// Scan state in LINEAR space with per-step power-of-2 renorm. Invariant:
//   E_b = 2^{R_b + PA + Q - Z}
//   S   = sum_b E_b*2^{a+sp0} = 2^{G(t)-Z}        =>  G = log2(S) + Z
//   E'  = (E_b*2^{a+sp1} + S*2^{st-AP2})*2^{-k},  Z += k
// -> dependency chain is mul/add/dpp only; exp2/log2 are off-chain.
constexpr int B  = 32;
constexpr int T  = 256;
constexpr int NB = 16;
#define INVLN2 1.4426950408889634f
#define LN2    0.6931471805599453f
#define AP2    (0.5f * 1.4426950408889634f)   // abstract pen, log2 units

__device__ __forceinline__ float fexp2(float x) { return exp2f(x); }
__device__ __forceinline__ float flog2(float x) { return __log2f(x); }

template<int C>
__device__ __forceinline__ float dppmv(float x) {
    return __int_as_float(__builtin_amdgcn_update_dpp(
        0, __float_as_int(x), C, 0xF, 0xF, true));
}

// 16-lane-group butterfly sum: xor1 (quad_perm 0xB1), xor2 (0x4E),
// xor7 (row_half_mirror 0x141), xor15 (row_mirror 0x140). Pure VALU pipe.
__device__ __forceinline__ float sum16(float x) {
    x += dppmv<0xB1>(x);
    x += dppmv<0x4E>(x);
    x += dppmv<0x141>(x);
    x += dppmv<0x140>(x);
    return x;
}

// One block per batch. Stage (log2-scaled) inputs to 64KB LDS, then
// wave 0 runs the forward scan, wave 1 the backward scan. Lane owns b=lane&15
// (lane groups 1-3 replicate; group 0 stores).
__global__ __launch_bounds__(256) void scan_kernel(
    const float* __restrict__ act_g,   // [B][T][16]
    const float* __restrict__ stp_g,   // [B][T+1][16][2] (orig e order)
    const float* __restrict__ str_g,   // [B][T+1][16]
    const int*   __restrict__ len_g,   // [B]
    float* __restrict__ Wbuf,          // [B][T+1]   log2 units
    float* __restrict__ TLbuf,         // [B]        log2 units
    float* __restrict__ Ubuf,          // [B][T][16] log2 units
    float* __restrict__ Vbuf)          // [B][T+1][16] log2 units
{
    __shared__ float sm[16384];                 // 64 KB
    float* act  = sm;                           // [256][16] rows 0..T-1
    float* stp  = sm + 4096;                    // [256][32] global rows 1..T
    float* strt = sm + 4096 + 8192;             // [256][16] rows 0..T-1

    const int beta = blockIdx.x;
    const int tid  = threadIdx.x;

    { // stage with 1/ln2 scaling
        const float4* a4 = (const float4*)(act_g + (size_t)beta * (T * NB));
        const float4* s4 = (const float4*)(stp_g + (size_t)beta * ((T + 1) * NB * 2) + 32);
        const float4* t4 = (const float4*)(str_g + (size_t)beta * ((T + 1) * NB));
        float4* actv = (float4*)act;
        float4* stpv = (float4*)stp;
        float4* strv = (float4*)strt;
        for (int i = tid; i < 1024; i += 256) {
            float4 v = a4[i];
            actv[i] = make_float4(v.x*INVLN2, v.y*INVLN2, v.z*INVLN2, v.w*INVLN2);
        }
        for (int i = tid; i < 2048; i += 256) {
            float4 v = s4[i];
            stpv[i] = make_float4(v.x*INVLN2, v.y*INVLN2, v.z*INVLN2, v.w*INVLN2);
        }
        for (int i = tid; i < 1024; i += 256) {
            float4 v = t4[i];
            strv[i] = make_float4(v.x*INVLN2, v.y*INVLN2, v.z*INVLN2, v.w*INVLN2);
        }
    }
    __syncthreads();

    const int wid  = tid >> 6;
    const int lane = tid & 63;
    const int b    = lane & 15;
    const int L    = len_g[beta];

    if (wid == 0) {
        // ---------------- forward (scaled linear) ----------------
        float* Ub = Ubuf + (size_t)beta * (T * NB);
        float* Vb = Vbuf + (size_t)beta * ((T + 1) * NB);
        float PA = 0.f, Q = 0.f, Z = 0.f, TL = 0.f;
        float u0 = strt[b] - AP2;              // U(b,0), log2
        float E  = fexp2(u0);                  // 2^{R_b} (PA=Q=Z=0)
        if (lane < 16) Ub[b] = u0;

        float  ca  = act[b];                                   // a(1)
        float2 cs  = *(const float2*)(stp + b * 2);            // sp(1): .x=e0 .y=e1
        float  cst = strt[16 + b];                             // st(1)

        for (int t = 1; t <= T; ++t) {
            // depth-1 prefetch (clamped; overflow rows unused)
            float  na  = act[(t & 255) * 16 + b];
            float2 ns  = *(const float2*)(stp + (t & 255) * 32 + b * 2);
            float  nst = strt[((t + 1) & 255) * 16 + b];

            float AP0 = fexp2(ca + cs.x);          // off-chain
            float S   = sum16(E * AP0);            // chain: mul + 4x(dpp+add)
            float G   = flog2(S) + Z;              // off-chain (output only); S = 2^{G-Z}
            if (t == L) TL = G;
            float V   = PA + ca + Q + cs.x;        // PA(t)+Q(t-1)+sp0
            PA += ca; Q += cs.y;
            if (lane < 16) Vb[t * 16 + b] = V;
            if (t < T) {
                float AP1 = fexp2(ca + cs.y);      // off-chain
                float Tb  = fexp2(cst - AP2);      // off-chain
                float U   = G + (cst - AP2) - PA - Q;
                if (lane < 16) Ub[t * 16 + b] = U;
                float En  = E * AP1 + S * Tb;      // chain: fma (E*AP1 parallel)
                unsigned e = (__float_as_uint(S) >> 23) & 0xFFu;
                float    r = __uint_as_float((254u - e) << 23);   // 2^{-(e-127)}
                E = En * r;                        // chain: mul
                Z += (float)((int)e - 127);        // exact integer accumulation
            }
            ca = na; cs = ns; cst = nst;
        }
        if (lane == 0) TLbuf[beta] = TL;
    } else if (wid == 1) {
        // ---------------- backward (scaled linear) ----------------
        // F0_b = 2^{fn0_b - Z}, F1 = 2^{fn1 - Z}; masked state = (0, 1, Z=0).
        float F0 = 0.f, F1 = 1.f, Z = 0.f;
        if (lane == 0) Wbuf[beta * (T + 1) + T] = 0.f;

        float  ca  = act[(T - 1) * 16 + b];
        float2 cs  = *(const float2*)(stp + (T - 1) * 32 + b * 2); // glob row T
        float  cst = strt[(T - 1) * 16 + b];

        for (int i = T - 1; i >= 0; --i) {
            const int pr = (i - 1) & 255;       // i=0 -> 255, unused
            float  na  = act[pr * 16 + b];
            float2 ns  = *(const float2*)(stp + pr * 32 + b * 2);
            float  nst = strt[pr * 16 + b];

            float AP1 = fexp2(ca + cs.y);       // pairs fn0 (rev e0 = orig e1)
            float AP0 = fexp2(ca + cs.x);       // pairs fn1 (rev e1 = orig e0)
            float Tb  = fexp2(cst - AP2);
            float F0n = AP1 * F0 + AP0 * F1;    // chain: fma
            float F1n = sum16(Tb * F0n);        // chain: mul + 4x(dpp+add)
            const bool mk = (i < L);
            float W = flog2(F1n) + Z;           // off-chain (output only)
            unsigned e = (__float_as_uint(F1n) >> 23) & 0xFFu;
            float    r = __uint_as_float((254u - e) << 23);
            F0 = mk ? F0n * r : 0.f;
            F1 = mk ? F1n * r : 1.f;
            Z  = mk ? Z + (float)((int)e - 127) : 0.f;
            if (i >= 1 && lane == 0) Wbuf[beta * (T + 1) + i] = mk ? W : 0.f;
            ca = na; cs = ns; cst = nst;
        }
    }
}

// One block per (beta, t). Partial sums to unique scratch slots (no atomics).
__global__ __launch_bounds__(256) void cc_kernel(
    const float* __restrict__ pens,   // [B][257][257][16]
    const int*   __restrict__ len_g,
    const float* __restrict__ Wbuf,
    const float* __restrict__ TLbuf,
    const float* __restrict__ Ubuf,
    const float* __restrict__ Vbuf,
    float* __restrict__ part)         // [T*B]
{
    const int beta = blockIdx.x;
    const int t    = blockIdx.y + 1;
    const int tid  = threadIdx.x;
    const int pidx = blockIdx.y * B + beta;
    const int L    = len_g[beta];
    if (t > L) { if (tid == 0) part[pidx] = 0.f; return; }

    const float c0 = Wbuf[beta * (T + 1) + t] - TLbuf[beta];   // log2
    const float4* U4 = (const float4*)(Ubuf + (size_t)beta * (T * NB));
    const float4* P4 = (const float4*)(pens + (size_t)beta * ((size_t)(T+1)*(T+1)*NB)
                                            + (size_t)t * NB);
    const int q = tid & 3;                     // constant per thread (stride 256 ≡ 0 mod 4)
    float4 vq = ((const float4*)(Vbuf + (size_t)beta * ((T + 1) * NB) + t * NB))[q];
    vq.x += c0; vq.y += c0; vq.z += c0; vq.w += c0;

    float local = 0.f;
    const int n4 = t * 4;                      // t rows x 4 float4
    for (int i4 = tid; i4 < n4; i4 += 256) {
        const int tau = i4 >> 2;
        float4 u = U4[i4];
        float4 p = P4[(size_t)tau * ((T + 1) * 4) + (i4 & 3)];
        local += fexp2(u.x + vq.x) * p.x + fexp2(u.y + vq.y) * p.y
               + fexp2(u.z + vq.z) * p.z + fexp2(u.w + vq.w) * p.w;
    }
#pragma unroll
    for (int off = 1; off < 64; off <<= 1) local += __shfl_xor(local, off);
    __shared__ float red[4];
    if ((tid & 63) == 0) red[tid >> 6] = local;
    __syncthreads();
    if (tid == 0) part[pidx] = red[0] + red[1] + red[2] + red[3];
}

// Reduce 8192 partials -> out[1]; reduce 32 TL -> out[0]. No atomics/memset.
__global__ __launch_bounds__(256) void final_kernel(
    const float* __restrict__ part, const float* __restrict__ TLbuf,
    float* __restrict__ out)
{
    const int tid = threadIdx.x;
    const float4* p4 = (const float4*)part;    // 2048 float4
    float s = 0.f;
#pragma unroll
    for (int k = 0; k < 8; ++k) {
        float4 v = p4[tid + 256 * k];
        s += v.x + v.y + v.z + v.w;
    }
#pragma unroll
    for (int off = 1; off < 64; off <<= 1) s += __shfl_xor(s, off);
    __shared__ float red[4];
    if ((tid & 63) == 0) red[tid >> 6] = s;
    __syncthreads();
    if (tid == 0) out[1] = red[0] + red[1] + red[2] + red[3];

    float tl = (tid < 32) ? TLbuf[tid] : 0.f;
    if (tid < 64) {
#pragma unroll
        for (int off = 1; off < 32; off <<= 1) tl += __shfl_xor(tl, off);
        if (tid == 0) out[0] = tl * LN2;
    }
}

extern "C" void kernel_launch(void* const* d_in, const int* in_sizes, int n_in,
                              void* d_out, int out_size, void* d_ws, size_t ws_size,
                              hipStream_t stream) {
    (void)in_sizes; (void)n_in; (void)out_size; (void)ws_size;
    const float* act  = (const float*)d_in[0];
    const float* stp  = (const float*)d_in[1];
    const float* strt = (const float*)d_in[2];
    const float* pens = (const float*)d_in[3];
    const int*   lens = (const int*)d_in[5];
    float* out = (float*)d_out;

    float* ws    = (float*)d_ws;
    float* Wbuf  = ws;                            // 8224
    float* TLbuf = Wbuf + B * (T + 1);            // 32
    float* Ubuf  = TLbuf + B;                     // 131072 (16B-aligned)
    float* Vbuf  = Ubuf + (size_t)B * T * NB;     // 131584
    float* part  = Vbuf + (size_t)B * (T+1) * NB; // 8192

    scan_kernel<<<B, 256, 0, stream>>>(act, stp, strt, lens, Wbuf, TLbuf, Ubuf, Vbuf);
    cc_kernel<<<dim3(B, T), 256, 0, stream>>>(pens, lens, Wbuf, TLbuf, Ubuf, Vbuf, part);
    final_kernel<<<1, 256, 0, stream>>>(part, TLbuf, out);
}

// Round 10
// 230.246 us; speedup vs baseline: 1.1361x; 1.1361x over previous
//
#include <hip/hip_runtime.h>

// CausalNet CC-loss. v3: issue-minimal serial scan + parallel pre/post phases.
// B=32, T=256, b=16 hardcoded.
//
//   marg(tau,t,b) = U(b,tau) + V(b,t) + W(t) - G(L)   (log2 units)
//   C(t)  = sum_{i<=t} (a_i + sp1_i)          [combined prefix, log2]
//   V(t)  = C(t) + sp0(t) - sp1(t)
//   U(t)  = G(t) + st(t) - AP2 - C(t),  U(0) = st(0) - AP2,  G(0)=0
//   G(t)  = log2(S_t) + Z_t  from scaled-linear forward recurrence:
//       E_b = 2^{R_b + C(t) - Z};  S = sum_b E_b*A0(t);  E' = (E*A1(t) + S*TB(t))*2^-k
//   W(t)  from scaled-linear backward recurrence (b-independent e=1 channel).
// Serial loops touch only precomputed LINEAR arrays A0,A1,TB (LDS) — no
// transcendentals, no U/V stores in-loop; raw {S,Z} pairs go to ws scratch.
constexpr int B  = 32;
constexpr int T  = 256;
constexpr int NB = 16;
#define INVLN2 1.4426950408889634f
#define LN2    0.6931471805599453f
#define AP2    (0.5f * 1.4426950408889634f)   // abstract pen, log2 units

__device__ __forceinline__ float fexp2(float x) { return exp2f(x); }
__device__ __forceinline__ float flog2(float x) { return __log2f(x); }

template<int C>
__device__ __forceinline__ float dppmv(float x) {
    return __int_as_float(__builtin_amdgcn_update_dpp(
        0, __float_as_int(x), C, 0xF, 0xF, true));
}

// 16-lane-group butterfly sum (all row-local DPP): xor1, xor2, xor7, xor15.
__device__ __forceinline__ float sum16(float x) {
    x += dppmv<0xB1>(x);
    x += dppmv<0x4E>(x);
    x += dppmv<0x141>(x);
    x += dppmv<0x140>(x);
    return x;
}

// One block per batch, 256 threads = 4 waves:
//   phase 1 (all): stage A0/A1/TB (linear) to LDS
//   phase 2: wave0 fwd scan, wave1 bwd scan, wave2 prefix C, wave3 idle
//   phase 3 (all): G/W/TL epilogue;  phase 4 (all): U/V float4 epilogue
__global__ __launch_bounds__(256) void scan_kernel(
    const float* __restrict__ act_g,   // [B][T][16]
    const float* __restrict__ stp_g,   // [B][T+1][16][2] (orig e order)
    const float* __restrict__ str_g,   // [B][T+1][16]
    const int*   __restrict__ len_g,   // [B]
    float* __restrict__ Wbuf,          // [B][T+1]     log2
    float* __restrict__ TLbuf,         // [B]          log2
    float* __restrict__ Ubuf,          // [B][T][16]   log2
    float* __restrict__ Vbuf,          // [B][T+1][16] log2
    float* __restrict__ SSbuf,         // [B][256][2]  fwd raw {S,Z}
    float* __restrict__ SBbuf)         // [B][256][2]  bwd raw {F1n,Z}
{
    __shared__ float sm[16384];        // 64 KB exactly
    float* A0 = sm;                    // [256][16]  2^{a(t)+sp0(t)}, t=1..256
    float* A1 = sm + 4096;             // [256][16]  2^{a(t)+sp1(t)}
    float* TB = sm + 8192;             // [256][16]  2^{st(r)-AP2}, r=0..255
    float* Cx = sm + 12288;            // [256][16]  C(t) at slot t-1
    float* Gs = TB;                    // aliases TB after scans complete

    const int beta = blockIdx.x;
    const int tid  = threadIdx.x;

    const float4* a4 = (const float4*)(act_g + (size_t)beta * (T * NB));
    const float4* s4 = (const float4*)(stp_g + (size_t)beta * ((T + 1) * NB * 2) + 32); // row 1+
    const float4* t4 = (const float4*)(str_g + (size_t)beta * ((T + 1) * NB));

    // ---- phase 1: stage linear arrays ----
    for (int i4 = tid; i4 < 1024; i4 += 256) {
        const int idx = i4 >> 2, q = i4 & 3;
        float4 a  = a4[i4];                       // act row idx, b=4q..4q+3
        float4 sA = s4[idx * 8 + q * 2];          // stp row idx+1: {b0e0,b0e1,b1e0,b1e1}
        float4 sB = s4[idx * 8 + q * 2 + 1];
        float4 st = t4[i4];                       // str row idx
        float4 v0, v1, vt;
        v0.x = fexp2((a.x + sA.x) * INVLN2); v1.x = fexp2((a.x + sA.y) * INVLN2);
        v0.y = fexp2((a.y + sA.z) * INVLN2); v1.y = fexp2((a.y + sA.w) * INVLN2);
        v0.z = fexp2((a.z + sB.x) * INVLN2); v1.z = fexp2((a.z + sB.y) * INVLN2);
        v0.w = fexp2((a.w + sB.z) * INVLN2); v1.w = fexp2((a.w + sB.w) * INVLN2);
        vt.x = fexp2(st.x * INVLN2 - AP2); vt.y = fexp2(st.y * INVLN2 - AP2);
        vt.z = fexp2(st.z * INVLN2 - AP2); vt.w = fexp2(st.w * INVLN2 - AP2);
        ((float4*)A0)[i4] = v0;
        ((float4*)A1)[i4] = v1;
        ((float4*)TB)[i4] = vt;
    }
    __syncthreads();

    const int wid  = tid >> 6;
    const int lane = tid & 63;
    const int b    = lane & 15;
    const int L    = len_g[beta];

    if (wid == 0) {
        // ---- forward: E_b = 2^{R_b + C - Z}; no transcendentals ----
        const float* A0b = A0 + b; const float* A1b = A1 + b; const float* TBb = TB + b;
        float2* ss = (float2*)(SSbuf + beta * 512);
        float E = TBb[0], Z = 0.f;                 // E = 2^{U(b,0)}
        float a0c = A0b[0],  a1c = A1b[0],  tbc = TBb[16];   // idx 0, TB row 1
        float a0n = A0b[16], a1n = A1b[16], tbn = TBb[32];   // idx 1, TB row 2
        for (int idx = 0; idx < 256; ++idx) {
            const int p = (idx + 2) & 255;
            float a0p = A0b[p * 16], a1p = A1b[p * 16], tbp = TBb[((idx + 3) & 255) * 16];
            float S = sum16(E * a0c);
            if (lane == 0) ss[idx] = make_float2(S, Z);
            if (idx < 255) {
                float En = E * a1c + S * tbc;
                unsigned e = (__float_as_uint(S) >> 23) & 0xFFu;
                E = En * __uint_as_float((254u - e) << 23);
                Z += (float)((int)e - 127);
            }
            a0c = a0n; a1c = a1n; tbc = tbn;
            a0n = a0p; a1n = a1p; tbn = tbp;
        }
    } else if (wid == 1) {
        // ---- backward: F0_b, F1 scalar chain; no transcendentals ----
        const float* A0b = A0 + b; const float* A1b = A1 + b; const float* TBb = TB + b;
        float2* sb = (float2*)(SBbuf + beta * 512);
        float F0 = 0.f, F1 = 1.f, Z = 0.f;
        float a0c = A0b[255 * 16], a1c = A1b[255 * 16], tbc = TBb[255 * 16];
        float a0n = A0b[254 * 16], a1n = A1b[254 * 16], tbn = TBb[254 * 16];
        for (int i = 255; i >= 0; --i) {
            const int p = (i - 2) & 255;
            float a0p = A0b[p * 16], a1p = A1b[p * 16], tbp = TBb[p * 16];
            float F0n = a1c * F0 + a0c * F1;
            float F1n = sum16(tbc * F0n);
            if (lane == 0) sb[i] = make_float2(F1n, Z);
            const bool mk = (i < L);
            unsigned e = (__float_as_uint(F1n) >> 23) & 0xFFu;
            float    r = __uint_as_float((254u - e) << 23);
            F0 = mk ? F0n * r : 0.f;
            F1 = mk ? F1n * r : 1.f;
            Z  = mk ? Z + (float)((int)e - 127) : 0.f;
            a0c = a0n; a1c = a1n; tbc = tbn;
            a0n = a0p; a1n = a1p; tbn = tbp;
        }
    } else if (wid == 2) {
        // ---- prefix C(t) = sum_{i<=t}(a_i+sp1_i), log2-scaled; 4 segs x 16 b ----
        const int seg = lane >> 4;
        const float* ap = act_g + (size_t)beta * 4096 + b;
        const float* sp = stp_g + (size_t)beta * 8224 + 32 + b * 2 + 1;  // row idx+1, e=1
        float s = 0.f;
#pragma unroll 8
        for (int k = 0; k < 64; ++k) {
            const int idx = seg * 64 + k;
            s += (ap[idx * 16] + sp[idx * 32]) * INVLN2;
        }
        float inc = s;
        float u1 = __shfl_up(inc, 16); if (lane >= 16) inc += u1;
        float u2 = __shfl_up(inc, 32); if (lane >= 32) inc += u2;
        float run = inc - s;                       // exclusive offset
#pragma unroll 8
        for (int k = 0; k < 64; ++k) {
            const int idx = seg * 64 + k;
            run += (ap[idx * 16] + sp[idx * 32]) * INVLN2;
            Cx[idx * 16 + b] = run;
        }
    }
    __syncthreads();

    // ---- phase 3: G, TL, W (parallel; Gs aliases dead TB) ----
    {
        float2 sz = ((const float2*)(SSbuf + beta * 512))[tid];
        float G = flog2(sz.x) + sz.y;              // G(tid+1)
        Gs[tid + 1] = G;
        if (tid == L - 1) TLbuf[beta] = G;
        if (tid >= 1) {
            float2 fz = ((const float2*)(SBbuf + beta * 512))[tid];
            Wbuf[beta * (T + 1) + tid] = (tid < L) ? flog2(fz.x) + fz.y : 0.f;
        } else {
            Wbuf[beta * (T + 1) + T] = 0.f;
        }
    }
    __syncthreads();

    // ---- phase 4: U/V rows (float4) ----
    float4* Ub4 = (float4*)(Ubuf + (size_t)beta * (T * NB));
    float4* Vb4 = (float4*)(Vbuf + (size_t)beta * ((T + 1) * NB));
    for (int i4 = tid; i4 < 1024; i4 += 256) {
        const int row = i4 >> 2, q = i4 & 3;
        float4 c  = ((const float4*)Cx)[i4];       // C(row+1)
        float4 sA = s4[row * 8 + q * 2];           // stp row row+1
        float4 sB = s4[row * 8 + q * 2 + 1];
        float4 V;
        V.x = c.x + (sA.x - sA.y) * INVLN2;
        V.y = c.y + (sA.z - sA.w) * INVLN2;
        V.z = c.z + (sB.x - sB.y) * INVLN2;
        V.w = c.w + (sB.z - sB.w) * INVLN2;
        Vb4[(row + 1) * 4 + q] = V;
        float4 st = t4[i4];                        // str row row
        float4 U;
        if (row == 0) {
            U.x = st.x * INVLN2 - AP2; U.y = st.y * INVLN2 - AP2;
            U.z = st.z * INVLN2 - AP2; U.w = st.w * INVLN2 - AP2;
        } else {
            float g = Gs[row];
            float4 cm = ((const float4*)Cx)[i4 - 4];   // C(row)
            U.x = g + st.x * INVLN2 - AP2 - cm.x;
            U.y = g + st.y * INVLN2 - AP2 - cm.y;
            U.z = g + st.z * INVLN2 - AP2 - cm.z;
            U.w = g + st.w * INVLN2 - AP2 - cm.w;
        }
        Ub4[i4] = U;
    }
}

// One block per (beta, t). Partial sums to unique scratch slots (no atomics).
__global__ __launch_bounds__(256) void cc_kernel(
    const float* __restrict__ pens,   // [B][257][257][16]
    const int*   __restrict__ len_g,
    const float* __restrict__ Wbuf,
    const float* __restrict__ TLbuf,
    const float* __restrict__ Ubuf,
    const float* __restrict__ Vbuf,
    float* __restrict__ part)         // [T*B]
{
    const int beta = blockIdx.x;
    const int t    = blockIdx.y + 1;
    const int tid  = threadIdx.x;
    const int pidx = blockIdx.y * B + beta;
    const int L    = len_g[beta];
    if (t > L) { if (tid == 0) part[pidx] = 0.f; return; }

    const float c0 = Wbuf[beta * (T + 1) + t] - TLbuf[beta];   // log2
    const float4* U4 = (const float4*)(Ubuf + (size_t)beta * (T * NB));
    const float4* P4 = (const float4*)(pens + (size_t)beta * ((size_t)(T+1)*(T+1)*NB)
                                            + (size_t)t * NB);
    const int q = tid & 3;
    float4 vq = ((const float4*)(Vbuf + (size_t)beta * ((T + 1) * NB) + t * NB))[q];
    vq.x += c0; vq.y += c0; vq.z += c0; vq.w += c0;

    float local = 0.f;
    const int n4 = t * 4;
    for (int i4 = tid; i4 < n4; i4 += 256) {
        const int tau = i4 >> 2;
        float4 u = U4[i4];
        float4 p = P4[(size_t)tau * ((T + 1) * 4) + (i4 & 3)];
        local += fexp2(u.x + vq.x) * p.x + fexp2(u.y + vq.y) * p.y
               + fexp2(u.z + vq.z) * p.z + fexp2(u.w + vq.w) * p.w;
    }
#pragma unroll
    for (int off = 1; off < 64; off <<= 1) local += __shfl_xor(local, off);
    __shared__ float red[4];
    if ((tid & 63) == 0) red[tid >> 6] = local;
    __syncthreads();
    if (tid == 0) part[pidx] = red[0] + red[1] + red[2] + red[3];
}

// Reduce 8192 partials -> out[1]; 32 TL -> out[0]. No atomics/memset.
__global__ __launch_bounds__(256) void final_kernel(
    const float* __restrict__ part, const float* __restrict__ TLbuf,
    float* __restrict__ out)
{
    const int tid = threadIdx.x;
    const float4* p4 = (const float4*)part;
    float s = 0.f;
#pragma unroll
    for (int k = 0; k < 8; ++k) {
        float4 v = p4[tid + 256 * k];
        s += v.x + v.y + v.z + v.w;
    }
#pragma unroll
    for (int off = 1; off < 64; off <<= 1) s += __shfl_xor(s, off);
    __shared__ float red[4];
    if ((tid & 63) == 0) red[tid >> 6] = s;
    __syncthreads();
    if (tid == 0) out[1] = red[0] + red[1] + red[2] + red[3];

    float tl = (tid < 32) ? TLbuf[tid] : 0.f;
    if (tid < 64) {
#pragma unroll
        for (int off = 1; off < 32; off <<= 1) tl += __shfl_xor(tl, off);
        if (tid == 0) out[0] = tl * LN2;
    }
}

extern "C" void kernel_launch(void* const* d_in, const int* in_sizes, int n_in,
                              void* d_out, int out_size, void* d_ws, size_t ws_size,
                              hipStream_t stream) {
    (void)in_sizes; (void)n_in; (void)out_size; (void)ws_size;
    const float* act  = (const float*)d_in[0];
    const float* stp  = (const float*)d_in[1];
    const float* strt = (const float*)d_in[2];
    const float* pens = (const float*)d_in[3];
    const int*   lens = (const int*)d_in[5];
    float* out = (float*)d_out;

    float* ws    = (float*)d_ws;
    float* Wbuf  = ws;                            // 8224
    float* TLbuf = Wbuf + B * (T + 1);            // 32
    float* Ubuf  = TLbuf + B;                     // 131072 (16B-aligned)
    float* Vbuf  = Ubuf + (size_t)B * T * NB;     // 131584
    float* part  = Vbuf + (size_t)B * (T+1) * NB; // 8192
    float* SSbuf = part + T * B;                  // 16384 (8B-aligned)
    float* SBbuf = SSbuf + B * 512;               // 16384

    scan_kernel<<<B, 256, 0, stream>>>(act, stp, strt, lens, Wbuf, TLbuf, Ubuf, Vbuf, SSbuf, SBbuf);
    cc_kernel<<<dim3(B, T), 256, 0, stream>>>(pens, lens, Wbuf, TLbuf, Ubuf, Vbuf, part);
    final_kernel<<<1, 256, 0, stream>>>(part, TLbuf, out);
}